// Round 5
// baseline (92.104 us; speedup 1.0000x reference)
//
#include <hip/hip_runtime.h>
#include <hip/hip_bf16.h>

#define Bn 8
#define Cn 3
#define Tn 32
#define Hn 128
#define Wn 128
#define HWn (Hn * Wn)          // 16384
#define Nn (Tn * HWn)          // 524288 elems per (b,c)
#define EPSn 1e-5f
#define RTn 32                 // 32 row-tiles (4 rows each)
#define NQ 4                   // 4-way t-split (8 output slices each)

__device__ __forceinline__ float silu_f(float v) {
    return v / (1.0f + __expf(-v));
}

// ========== K12: fused spatial 3x3 conv + temporal 7-tap conv + all analytics ==========
// Block = (rt, b, qtr): 4 rows x 128 cols, 256 threads = 4 waves; wave = one row,
// thread = 2 px. No LDS for x: vertical halo via direct loads of rows h-1/h/h+1
// (L1/L2-hot), horizontal halo via __shfl_up/down. t streamed with a 7-deep register
// ring (3 ch x float2); t split in 4 quarters (3/2-slice halo) -> 1024 blocks.
// No per-t __syncthreads. Outputs:
//   raw0/raw1[qtr][bc][s]    = partial sum_t wks{0,1}[t]*g      (kv_s contraction)
//   pt0p/pt1p[bc][t][rt]     = partial sum_s g*wkt{0,1}[s]      (kv_t contraction)
//   ss0p/ss1p[bc][rt*4+qtr]  = partial {sum g, sum g^2}         (SwitchNorm stats)
template<int QTR>
__device__ __forceinline__ void k12_body(
    const float* __restrict__ x, const float* __restrict__ wsp,
    const float* __restrict__ bsp, const float* __restrict__ wtp,
    const float* __restrict__ btp, const float* __restrict__ wkt,
    const float* __restrict__ wks,
    float* __restrict__ raw0, float* __restrict__ raw1,
    float* __restrict__ pt0p, float* __restrict__ pt1p,
    float* __restrict__ ss0p, float* __restrict__ ss1p)
{
    constexpr int O0 = QTR * 8;
    constexpr int O1 = O0 + 8;
    constexpr int SLO = (O0 - 3 < 0) ? 0 : (O0 - 3);
    constexpr int SHI = (O1 + 2 > Tn - 1) ? (Tn - 1) : (O1 + 2);

    const int rt = blockIdx.x;          // 0..31
    const int b  = blockIdx.y;          // 0..7
    const int tid = threadIdx.x, lane = tid & 63, wave = tid >> 6;
    const int h = rt * 4 + wave;        // global row, wave owns it
    const int col = lane * 2;

    __shared__ float wred[8][6][33];    // per-t kv_t partials (8-lane groups), 6.3 KB
    __shared__ float redf[6][4];

    // uniform weights -> scalar regs
    float wsp_r[27], bsp_r[3], wt_r[21], bt_r[3];
#pragma unroll
    for (int i = 0; i < 27; ++i) wsp_r[i] = wsp[i];
#pragma unroll
    for (int i = 0; i < 3; ++i) bsp_r[i] = bsp[i];
#pragma unroll
    for (int i = 0; i < 21; ++i) wt_r[i] = wtp[i];
#pragma unroll
    for (int i = 0; i < 3; ++i) bt_r[i] = btp[i];

    const float* xb = x + (size_t)b * Nn + (size_t)h * Wn + col;
    const bool upok = h > 0, dnok = h < Hn - 1;

    const float2 k0v = *(const float2*)(wkt + h * Wn + col);
    const float2 k1v = *(const float2*)(wkt + HWn + h * Wn + col);

    float2 ring[7][3];
    float2 a0[3], a1[3];
    float ps[3], pq[3];
#pragma unroll
    for (int c = 0; c < 3; ++c) {
        a0[c] = make_float2(0.f, 0.f); a1[c] = make_float2(0.f, 0.f);
        ps[c] = 0.f; pq[c] = 0.f;
    }

#pragma unroll
    for (int tt = SLO; tt <= SHI + 3; ++tt) {
        if (tt <= SHI) {
            const float* xsl = xb + (size_t)tt * HWn;
            float2 xm = upok ? *(const float2*)(xsl - Wn) : make_float2(0.f, 0.f);
            float2 xc = *(const float2*)(xsl);
            float2 xp = dnok ? *(const float2*)(xsl + Wn) : make_float2(0.f, 0.f);
            float xv[3][4];
            {
                float lu, rd;
                lu = __shfl_up(xm.y, 1);  rd = __shfl_down(xm.x, 1);
                xv[0][0] = (lane == 0) ? 0.f : lu; xv[0][1] = xm.x; xv[0][2] = xm.y;
                xv[0][3] = (lane == 63) ? 0.f : rd;
                lu = __shfl_up(xc.y, 1);  rd = __shfl_down(xc.x, 1);
                xv[1][0] = (lane == 0) ? 0.f : lu; xv[1][1] = xc.x; xv[1][2] = xc.y;
                xv[1][3] = (lane == 63) ? 0.f : rd;
                lu = __shfl_up(xp.y, 1);  rd = __shfl_down(xp.x, 1);
                xv[2][0] = (lane == 0) ? 0.f : lu; xv[2][1] = xp.x; xv[2][2] = xp.y;
                xv[2][3] = (lane == 63) ? 0.f : rd;
            }
#pragma unroll
            for (int c = 0; c < 3; ++c) {
                float s0 = bsp_r[c], s1 = bsp_r[c];
#pragma unroll
                for (int i = 0; i < 3; ++i) {
#pragma unroll
                    for (int j = 0; j < 3; ++j) {
                        const float wv = wsp_r[c * 9 + i * 3 + j];
                        s0 += wv * xv[i][j];
                        s1 += wv * xv[i][j + 1];
                    }
                }
                ring[tt % 7][c].x = silu_f(s0);
                ring[tt % 7][c].y = silu_f(s1);
            }
        }
        const int to = tt - 3;
        if (to >= O0 && to < O1) {          // compile-time pruned per unrolled iter
            float g0[3], g1[3];
            const float wk0 = wks[to];      // uniform scalar loads (hoisted by unroll)
            const float wk1 = wks[Tn + to];
#pragma unroll
            for (int c = 0; c < 3; ++c) {
                float t0 = bt_r[c], t1 = bt_r[c];
#pragma unroll
                for (int k = 0; k < 7; ++k) {
                    const int ts = to + k - 3;
                    if (ts >= 0 && ts < Tn) {   // compile-time
                        const float wv = wt_r[c * 7 + k];
                        t0 += wv * ring[ts % 7][c].x;
                        t1 += wv * ring[ts % 7][c].y;
                    }
                }
                t0 = silu_f(silu_f(t0)); t1 = silu_f(silu_f(t1));
                g0[c] = t0; g1[c] = t1;
                a0[c].x += wk0 * t0; a0[c].y += wk0 * t1;
                a1[c].x += wk1 * t0; a1[c].y += wk1 * t1;
                ps[c] += t0 + t1;
                pq[c] += t0 * t0 + t1 * t1;
            }
            float pv[6];
#pragma unroll
            for (int c = 0; c < 3; ++c) {
                pv[c * 2 + 0] = k0v.x * g0[c] + k0v.y * g1[c];
                pv[c * 2 + 1] = k1v.x * g0[c] + k1v.y * g1[c];
            }
#pragma unroll
            for (int v = 0; v < 6; ++v) {
                pv[v] += __shfl_xor(pv[v], 1, 64);
                pv[v] += __shfl_xor(pv[v], 2, 64);
                pv[v] += __shfl_xor(pv[v], 4, 64);
            }
            const int j = lane & 7;
            if (j < 6) {
                const float val = (j == 0) ? pv[0] : (j == 1) ? pv[1] : (j == 2) ? pv[2]
                                : (j == 3) ? pv[3] : (j == 4) ? pv[4] : pv[5];
                wred[to - O0][j][(wave << 3) | (lane >> 3)] = val;
            }
        }
    }

    // --- block-reduce ps/pq ---
    float sv[6] = { ps[0], ps[1], ps[2], pq[0], pq[1], pq[2] };
#pragma unroll
    for (int v = 0; v < 6; ++v) {
#pragma unroll
        for (int d = 1; d < 64; d <<= 1) sv[v] += __shfl_xor(sv[v], d, 64);
    }
    if (lane == 0) {
#pragma unroll
        for (int v = 0; v < 6; ++v) redf[v][wave] = sv[v];
    }
    __syncthreads();
    if (tid < 3) {
        ss0p[(size_t)(b * 3 + tid) * (RTn * NQ) + rt * NQ + QTR] =
            redf[tid][0] + redf[tid][1] + redf[tid][2] + redf[tid][3];
    } else if (tid < 6) {
        ss1p[(size_t)(b * 3 + tid - 3) * (RTn * NQ) + rt * NQ + QTR] =
            redf[tid][0] + redf[tid][1] + redf[tid][2] + redf[tid][3];
    }
    // --- reduce wred -> pt partials (8 local t x 6 vals) ---
    if (tid < 48) {
        const int t = tid / 6, cv = tid % 6;
        float s0 = 0.f, s1 = 0.f, s2 = 0.f, s3 = 0.f;
#pragma unroll
        for (int i = 0; i < 32; i += 4) {
            s0 += wred[t][cv][i]; s1 += wred[t][cv][i + 1];
            s2 += wred[t][cv][i + 2]; s3 += wred[t][cv][i + 3];
        }
        const int c = cv >> 1, v = cv & 1;
        float* dst = v ? pt1p : pt0p;
        dst[((size_t)(b * 3 + c) * Tn + O0 + t) * RTn + rt] = (s0 + s1) + (s2 + s3);
    }
    // --- raw kv_s stores (per-quarter buffers) ---
#pragma unroll
    for (int c = 0; c < 3; ++c) {
        const size_t off = (size_t)(QTR * 24 + b * 3 + c) * HWn + (size_t)h * Wn + col;
        *(float2*)(raw0 + off) = a0[c];
        *(float2*)(raw1 + off) = a1[c];
    }
}

__global__ __launch_bounds__(256) void k12_conv(
    const float* __restrict__ x, const float* __restrict__ wsp,
    const float* __restrict__ bsp, const float* __restrict__ wtp,
    const float* __restrict__ btp, const float* __restrict__ wkt,
    const float* __restrict__ wks,
    float* __restrict__ raw0, float* __restrict__ raw1,
    float* __restrict__ pt0p, float* __restrict__ pt1p,
    float* __restrict__ ss0p, float* __restrict__ ss1p)
{
    switch (blockIdx.z) {
    case 0: k12_body<0>(x, wsp, bsp, wtp, btp, wkt, wks, raw0, raw1, pt0p, pt1p, ss0p, ss1p); break;
    case 1: k12_body<1>(x, wsp, bsp, wtp, btp, wkt, wks, raw0, raw1, pt0p, pt1p, ss0p, ss1p); break;
    case 2: k12_body<2>(x, wsp, bsp, wtp, btp, wkt, wks, raw0, raw1, pt0p, pt1p, ss0p, ss1p); break;
    default: k12_body<3>(x, wsp, bsp, wtp, btp, wkt, wks, raw0, raw1, pt0p, pt1p, ss0p, ss1p); break;
    }
}

// ========== K3: reduce partials + SwitchNorm stats + kv_t softmax -> A, scale/shift ==========
__global__ __launch_bounds__(256) void k3_finalize(
    const float* __restrict__ pt0p, const float* __restrict__ pt1p,
    const float* __restrict__ ss0p, const float* __restrict__ ss1p,
    const float* __restrict__ mean_w, const float* __restrict__ var_w,
    const float* __restrict__ snw, const float* __restrict__ snb,
    const float* __restrict__ wkt, const float* __restrict__ wks,
    float* __restrict__ scale, float* __restrict__ shift,
    float* __restrict__ A, float* __restrict__ wsum)
{
    const int tid = threadIdx.x;
    __shared__ float kvt0[Bn * Cn * Tn], kvt1[Bn * Cn * Tn];
    // pt reduce: 768 rows x 32, ILP-4 accumulators
    for (int i = tid; i < Bn * Cn * Tn; i += 256) {
        const float* p0 = pt0p + (size_t)i * RTn;
        const float* p1 = pt1p + (size_t)i * RTn;
        float a0 = 0.f, a1 = 0.f, a2 = 0.f, a3 = 0.f;
        float b0 = 0.f, b1 = 0.f, b2 = 0.f, b3 = 0.f;
#pragma unroll
        for (int j = 0; j < RTn; j += 4) {
            a0 += p0[j]; a1 += p0[j + 1]; a2 += p0[j + 2]; a3 += p0[j + 3];
            b0 += p1[j]; b1 += p1[j + 1]; b2 += p1[j + 2]; b3 += p1[j + 3];
        }
        kvt0[i] = (a0 + a1) + (a2 + a3);
        kvt1[i] = (b0 + b1) + (b2 + b3);
    }
    // ss reduce: 24 rows x 128, 8 threads per row
    __shared__ float ssr0[24][8], ssr1[24][8];
    if (tid < 192) {
        const int bc = tid >> 3, part = tid & 7;
        const float* p0 = ss0p + (size_t)bc * (RTn * NQ) + part * 16;
        const float* p1 = ss1p + (size_t)bc * (RTn * NQ) + part * 16;
        float a0 = 0.f, a1 = 0.f, b0 = 0.f, b1 = 0.f;
#pragma unroll
        for (int j = 0; j < 16; j += 2) {
            a0 += p0[j]; a1 += p0[j + 1];
            b0 += p1[j]; b1 += p1[j + 1];
        }
        ssr0[bc][part] = a0 + a1;
        ssr1[bc][part] = b0 + b1;
    }
    __shared__ float red0[256], red1[256];
    float l0 = 0.f, l1 = 0.f;
    for (int i = tid; i < HWn; i += 256) { l0 += wkt[i]; l1 += wkt[HWn + i]; }
    red0[tid] = l0; red1[tid] = l1;
    __syncthreads();
    for (int off = 128; off > 0; off >>= 1) {
        if (tid < off) { red0[tid] += red0[tid + off]; red1[tid] += red1[tid + off]; }
        __syncthreads();
    }
    __shared__ float sWt0, sWt1;
    __shared__ float sh_mean[24], sh_var[24], sh_temp[24];
    __shared__ float sh_mln[8], sh_vln[8], sh_mbn[3], sh_vbn[3];
    __shared__ float sh_mw[3], sh_vw[3];
    __shared__ float sh_scale[24], sh_shift[24];
    if (tid == 0) {
        sWt0 = red0[0]; sWt1 = red1[0];
        float a = 0.f, bb = 0.f;
        for (int t = 0; t < Tn; ++t) { a += wks[t]; bb += wks[Tn + t]; }
        wsum[0] = sWt0; wsum[1] = sWt1; wsum[2] = a; wsum[3] = bb;
    }
    if (tid < 24) {
        float S = 0.f, SS = 0.f;
#pragma unroll
        for (int j = 0; j < 8; ++j) { S += ssr0[tid][j]; SS += ssr1[tid][j]; }
        const float Nf = (float)Nn;
        float mean = S / Nf;
        float var = (SS - S * mean) / (Nf - 1.0f);   // unbiased (ddof=1)
        sh_mean[tid] = mean; sh_var[tid] = var; sh_temp[tid] = var + mean * mean;
    }
    __syncthreads();
    if (tid == 0) {
        for (int b = 0; b < Bn; ++b) {
            float m = 0.f, tp = 0.f;
            for (int c = 0; c < Cn; ++c) { m += sh_mean[b * 3 + c]; tp += sh_temp[b * 3 + c]; }
            m *= (1.0f / 3.0f); tp *= (1.0f / 3.0f);
            sh_mln[b] = m; sh_vln[b] = tp - m * m;
        }
        for (int c = 0; c < Cn; ++c) {
            float m = 0.f, tp = 0.f;
            for (int b = 0; b < Bn; ++b) { m += sh_mean[b * 3 + c]; tp += sh_temp[b * 3 + c]; }
            m *= 0.125f; tp *= 0.125f;
            sh_mbn[c] = m; sh_vbn[c] = tp - m * m;
        }
        {
            float m0 = mean_w[0], m1 = mean_w[1], m2 = mean_w[2];
            float mm = fmaxf(m0, fmaxf(m1, m2));
            float e0 = __expf(m0 - mm), e1 = __expf(m1 - mm), e2 = __expf(m2 - mm);
            float inv = 1.0f / (e0 + e1 + e2);
            sh_mw[0] = e0 * inv; sh_mw[1] = e1 * inv; sh_mw[2] = e2 * inv;
        }
        {
            float v0 = var_w[0], v1 = var_w[1], v2 = var_w[2];
            float vm = fmaxf(v0, fmaxf(v1, v2));
            float e0 = __expf(v0 - vm), e1 = __expf(v1 - vm), e2 = __expf(v2 - vm);
            float inv = 1.0f / (e0 + e1 + e2);
            sh_vw[0] = e0 * inv; sh_vw[1] = e1 * inv; sh_vw[2] = e2 * inv;
        }
    }
    __syncthreads();
    if (tid < 24) {
        int b = tid / 3, c = tid % 3;
        float mean = sh_mw[0] * sh_mean[tid] + sh_mw[1] * sh_mln[b] + sh_mw[2] * sh_mbn[c];
        float var  = sh_vw[0] * sh_var[tid]  + sh_vw[1] * sh_vln[b] + sh_vw[2] * sh_vbn[c];
        float inv = 1.0f / sqrtf(var + EPSn);
        float sc = inv * snw[c];
        float sf = snb[c] - mean * sc;
        sh_scale[tid] = sc; sh_shift[tid] = sf;
        scale[tid] = sc; shift[tid] = sf;
    }
    __syncthreads();
    for (int i = tid; i < Bn * Cn * Tn; i += 256) {
        int bc = i >> 5;
        kvt0[i] = sh_scale[bc] * kvt0[i] + sh_shift[bc] * sWt0;
        kvt1[i] = sh_scale[bc] * kvt1[i] + sh_shift[bc] * sWt1;
    }
    __syncthreads();
    if (tid < 24) {
        float m = -3.4e38f;
        for (int t = 0; t < Tn; ++t) m = fmaxf(m, kvt0[tid * Tn + t]);
        float se = 0.f;
        for (int t = 0; t < Tn; ++t) se += __expf(kvt0[tid * Tn + t] - m);
        float inv = 1.0f / se;
        for (int t = 0; t < Tn; ++t)
            A[tid * Tn + t] = sqrtf(__expf(kvt0[tid * Tn + t] - m) * inv) * kvt1[tid * Tn + t];
    }
}

// ========== K5a: per-chunk max/expsum of the s-softmax input (quarters summed) ==========
__global__ __launch_bounds__(256) void k5a_maxsum(
    const float* __restrict__ raw0, const float* __restrict__ scale,
    const float* __restrict__ shift, const float* __restrict__ wsum,
    float2* __restrict__ ms)
{
    const int ch = blockIdx.x;   // 0..7 (chunks of 2048)
    const int bc = blockIdx.y;   // 0..23
    const int tid = threadIdx.x, lane = tid & 63, wave = tid >> 6;
    const float sc = scale[bc], c0 = shift[bc] * wsum[2];
    const float* pa = raw0 + (size_t)bc * HWn + ch * 2048 + tid * 8;
    float4 q0a = ((const float4*)pa)[0], q0b = ((const float4*)pa)[1];
    float4 q1a = ((const float4*)(pa + (size_t)24 * HWn))[0],
           q1b = ((const float4*)(pa + (size_t)24 * HWn))[1];
    float4 q2a = ((const float4*)(pa + (size_t)48 * HWn))[0],
           q2b = ((const float4*)(pa + (size_t)48 * HWn))[1];
    float4 q3a = ((const float4*)(pa + (size_t)72 * HWn))[0],
           q3b = ((const float4*)(pa + (size_t)72 * HWn))[1];
    float vals[8] = { (q0a.x + q1a.x) + (q2a.x + q3a.x), (q0a.y + q1a.y) + (q2a.y + q3a.y),
                      (q0a.z + q1a.z) + (q2a.z + q3a.z), (q0a.w + q1a.w) + (q2a.w + q3a.w),
                      (q0b.x + q1b.x) + (q2b.x + q3b.x), (q0b.y + q1b.y) + (q2b.y + q3b.y),
                      (q0b.z + q1b.z) + (q2b.z + q3b.z), (q0b.w + q1b.w) + (q2b.w + q3b.w) };
    float m = -3.4e38f;
#pragma unroll
    for (int i = 0; i < 8; ++i) m = fmaxf(m, sc * vals[i] + c0);
#pragma unroll
    for (int d = 1; d < 64; d <<= 1) m = fmaxf(m, __shfl_xor(m, d, 64));
    __shared__ float wm[4], wsm[4];
    if (lane == 0) wm[wave] = m;
    __syncthreads();
    const float M = fmaxf(fmaxf(wm[0], wm[1]), fmaxf(wm[2], wm[3]));
    float s = 0.f;
#pragma unroll
    for (int i = 0; i < 8; ++i) s += __expf(sc * vals[i] + c0 - M);
#pragma unroll
    for (int d = 1; d < 64; d <<= 1) s += __shfl_xor(s, d, 64);
    if (lane == 0) wsm[wave] = s;
    __syncthreads();
    if (tid == 0) {
        float2 o; o.x = M; o.y = wsm[0] + wsm[1] + wsm[2] + wsm[3];
        ms[bc * 8 + ch] = o;
    }
}

// ========== K6: B finalize inline + outer product out[bc,t,s] = A[t]*B[s] ==========
__global__ __launch_bounds__(256) void k6_outer(
    const float* __restrict__ raw0, const float* __restrict__ raw1,
    const float* __restrict__ scale, const float* __restrict__ shift,
    const float* __restrict__ wsum, const float2* __restrict__ ms,
    const float* __restrict__ A, float* __restrict__ out)
{
    const int ch = blockIdx.x;   // 0..15 (chunks of 1024)
    const int bc = blockIdx.y;   // 0..23
    const int tid = threadIdx.x;
    __shared__ float a[Tn];
    if (tid < Tn) a[tid] = A[bc * Tn + tid];
    const float sc = scale[bc], sf = shift[bc];
    const float c0 = sf * wsum[2], c1 = sf * wsum[3];
    float M = -3.4e38f;
#pragma unroll
    for (int j = 0; j < 8; ++j) M = fmaxf(M, ms[bc * 8 + j].x);
    float S = 0.f;
#pragma unroll
    for (int j = 0; j < 8; ++j) S += ms[bc * 8 + j].y * __expf(ms[bc * 8 + j].x - M);
    const float invS = 1.0f / S;
    const int s = ch * 1024 + tid * 4;
    const float* p0 = raw0 + (size_t)bc * HWn + s;
    const float* p1 = raw1 + (size_t)bc * HWn + s;
    float4 r0 = *(const float4*)p0;
    float4 r1 = *(const float4*)p1;
#pragma unroll
    for (int q = 1; q < NQ; ++q) {
        float4 t0 = *(const float4*)(p0 + (size_t)q * 24 * HWn);
        float4 t1 = *(const float4*)(p1 + (size_t)q * 24 * HWn);
        r0.x += t0.x; r0.y += t0.y; r0.z += t0.z; r0.w += t0.w;
        r1.x += t1.x; r1.y += t1.y; r1.z += t1.z; r1.w += t1.w;
    }
    float4 Bv;
    Bv.x = sqrtf(__expf(sc * r0.x + c0 - M) * invS) * (sc * r1.x + c1);
    Bv.y = sqrtf(__expf(sc * r0.y + c0 - M) * invS) * (sc * r1.y + c1);
    Bv.z = sqrtf(__expf(sc * r0.z + c0 - M) * invS) * (sc * r1.z + c1);
    Bv.w = sqrtf(__expf(sc * r0.w + c0 - M) * invS) * (sc * r1.w + c1);
    __syncthreads();
    float* op = out + (size_t)bc * Nn + s;
#pragma unroll
    for (int t = 0; t < Tn; ++t) {
        const float av = a[t];
        float4 o; o.x = av * Bv.x; o.y = av * Bv.y; o.z = av * Bv.z; o.w = av * Bv.w;
        *(float4*)(op + (size_t)t * HWn) = o;
    }
}

extern "C" void kernel_launch(void* const* d_in, const int* in_sizes, int n_in,
                              void* d_out, int out_size, void* d_ws, size_t ws_size,
                              hipStream_t stream) {
    const float* x          = (const float*)d_in[0];
    const float* w_spatial  = (const float*)d_in[1];
    const float* b_spatial  = (const float*)d_in[2];
    const float* w_temporal = (const float*)d_in[3];
    const float* b_temporal = (const float*)d_in[4];
    const float* sn_weight  = (const float*)d_in[5];
    const float* sn_bias    = (const float*)d_in[6];
    const float* mean_weight= (const float*)d_in[7];
    const float* var_weight = (const float*)d_in[8];
    const float* w_kv_s     = (const float*)d_in[9];
    const float* w_kv_t     = (const float*)d_in[10];
    float* out = (float*)d_out;
    float* ws  = (float*)d_ws;

    // ws layout (floats)
    float* raw0  = ws;                                   // [NQ][24][HWn] = 1572864
    float* raw1  = raw0 + (size_t)NQ * Bn * Cn * HWn;    // 1572864
    float* pt0p  = raw1 + (size_t)NQ * Bn * Cn * HWn;    // 24*32*32 = 24576
    float* pt1p  = pt0p + (size_t)Bn * Cn * Tn * RTn;    // 24576
    float* ss0p  = pt1p + (size_t)Bn * Cn * Tn * RTn;    // 24*128 = 3072
    float* ss1p  = ss0p + (size_t)Bn * Cn * RTn * NQ;    // 3072
    float* scale = ss1p + (size_t)Bn * Cn * RTn * NQ;    // 24
    float* shift = scale + 24;                           // 24
    float* A     = shift + 24;                           // 768
    float* wsum  = A + Bn * Cn * Tn;                     // 4
    float2* ms   = (float2*)(wsum + 4);                  // 192 float2

    k12_conv<<<dim3(RTn, Bn, NQ), 256, 0, stream>>>(x, w_spatial, b_spatial,
                                                    w_temporal, b_temporal,
                                                    w_kv_t, w_kv_s,
                                                    raw0, raw1, pt0p, pt1p, ss0p, ss1p);
    k3_finalize<<<1, 256, 0, stream>>>(pt0p, pt1p, ss0p, ss1p,
                                       mean_weight, var_weight, sn_weight, sn_bias,
                                       w_kv_t, w_kv_s, scale, shift, A, wsum);
    k5a_maxsum<<<dim3(8, Bn * Cn), 256, 0, stream>>>(raw0, scale, shift, wsum, ms);
    k6_outer<<<dim3(16, Bn * Cn), 256, 0, stream>>>(raw0, raw1, scale, shift, wsum,
                                                    ms, A, out);
}